// Round 3
// baseline (3943.706 us; speedup 1.0000x reference)
//
#include <hip/hip_runtime.h>
#include <hip/hip_bf16.h>
#include <math.h>

// Problem constants (from reference setup_inputs)
#define BB   32
#define TT_  8192
#define QD   512
#define VD   256
#define DD   128
#define TINYF 1.17549435e-38f

// Tiling for the score kernel
#define TTILE 64   // t rows per block
#define CCH   32   // c-chunk

// Speculation window: scores computed eagerly for t < TSPEC. E[log(1-p)]
// ~ -0.8/step -> cumsum ~ -205 at t=256, far below fp32 exp underflow (-104).
// If the exclusive cumprod has NOT underflowed to exactly 0 by t=TSPEC, the
// fused kernel falls back to an in-block score+scan continuation (slow but
// correct; never taken on this data distribution).
#define TSPEC 256
#define TSPEC_TILES (TSPEC / TTILE)   // 4

// ---------------- Kernel 1: window scores (q recomputed in-block) ----------
// score[b][t] = sum_d attv[d]*tanh(q[b][d]+bv[d] + (value[b][t]@Wv)[d]) + sbias
__global__ __launch_bounds__(256) void k_score(
    const float* __restrict__ value, const float* __restrict__ query,
    const float* __restrict__ Wq, const float* __restrict__ bq,
    const float* __restrict__ Wv, const float* __restrict__ bv,
    const float* __restrict__ attv, const float* __restrict__ sbias,
    float* __restrict__ score) {
  int b = blockIdx.y;
  int tid = threadIdx.x;

  // ---- recompute q[b][:] + bq + bv into LDS (cheap: 256 FMA/thread) ----
  __shared__ float qrow[QD];
  __shared__ float qpart[2][DD];
  __shared__ float qsh[DD];
  qrow[tid]       = query[b * QD + tid];
  qrow[tid + 256] = query[b * QD + tid + 256];
  __syncthreads();
  {
    int h = tid >> 7, d = tid & 127;
    const float* wq = Wq + (size_t)(h * 256) * DD + d;
    const float* qr = qrow + h * 256;
    float acc = 0.f;
    #pragma unroll 8
    for (int c = 0; c < 256; ++c) acc = fmaf(qr[c], wq[(size_t)c * DD], acc);
    qpart[h][d] = acc;
  }
  __syncthreads();
  if (tid < DD) qsh[tid] = qpart[0][tid] + qpart[1][tid] + bq[tid] + bv[tid];
  __syncthreads();

  // ---- register-tiled GEMM: (value tile) @ Wv ----
  int t0 = blockIdx.x * TTILE;
  int dq = tid & 31;   // d-group of 4
  int tq = tid >> 5;   // t-group of 8

  __shared__ float WvL[CCH * DD];
  __shared__ float valT[CCH * 68];

  float acc[8][4];
  #pragma unroll
  for (int i = 0; i < 8; ++i)
    #pragma unroll
    for (int j = 0; j < 4; ++j) acc[i][j] = 0.f;

  const float* vbase = value + ((size_t)b * TT_ + t0) * VD;

  for (int c0 = 0; c0 < VD; c0 += CCH) {
    const float4* wsrc = (const float4*)(Wv + (size_t)c0 * DD);
    float4* wdst = (float4*)WvL;
    #pragma unroll
    for (int k = 0; k < 4; ++k) wdst[tid + 256 * k] = wsrc[tid + 256 * k];
    #pragma unroll
    for (int k = 0; k < 2; ++k) {
      int id = tid * 2 + k;
      int tt = id >> 3;
      int c4 = id & 7;
      float4 vv = *(const float4*)(vbase + (size_t)tt * VD + c0 + c4 * 4);
      int cr = c4 * 4;
      valT[(cr + 0) * 68 + tt] = vv.x;
      valT[(cr + 1) * 68 + tt] = vv.y;
      valT[(cr + 2) * 68 + tt] = vv.z;
      valT[(cr + 3) * 68 + tt] = vv.w;
    }
    __syncthreads();
    #pragma unroll 4
    for (int cc = 0; cc < CCH; ++cc) {
      const float4 wv  = *(const float4*)(&WvL[cc * DD + dq * 4]);
      const float4 va0 = *(const float4*)(&valT[cc * 68 + tq * 8]);
      const float4 va1 = *(const float4*)(&valT[cc * 68 + tq * 8 + 4]);
      float va[8] = {va0.x, va0.y, va0.z, va0.w, va1.x, va1.y, va1.z, va1.w};
      #pragma unroll
      for (int i = 0; i < 8; ++i) {
        acc[i][0] = fmaf(va[i], wv.x, acc[i][0]);
        acc[i][1] = fmaf(va[i], wv.y, acc[i][1]);
        acc[i][2] = fmaf(va[i], wv.z, acc[i][2]);
        acc[i][3] = fmaf(va[i], wv.w, acc[i][3]);
      }
    }
    __syncthreads();
  }

  float sb = sbias[0];
  float qd[4], av[4];
  #pragma unroll
  for (int j = 0; j < 4; ++j) {
    int d = dq * 4 + j;
    qd[j] = qsh[d];
    av[j] = attv[d];
  }
  #pragma unroll
  for (int i = 0; i < 8; ++i) {
    float s = 0.f;
    #pragma unroll
    for (int j = 0; j < 4; ++j) {
      float x = qd[j] + acc[i][j];
      s += av[j] * tanhf(x);
    }
    #pragma unroll
    for (int m = 16; m >= 1; m >>= 1) s += __shfl_xor(s, m, 64);
    if (dq == 0) score[(size_t)b * TT_ + t0 + tq * 8 + i] = s + sb;
  }
}

// ------- Kernel 2: fused scan + tail-zero + u + ctx (+ in-block fallback) ---
__global__ __launch_bounds__(256) void k_fused(
    const float* __restrict__ score, const float* __restrict__ prev,
    const float* __restrict__ value, const float* __restrict__ query,
    const float* __restrict__ Wq, const float* __restrict__ bq,
    const float* __restrict__ Wv, const float* __restrict__ bv,
    const float* __restrict__ attv, const float* __restrict__ sbias,
    float* __restrict__ align_out, float* __restrict__ ctx) {
  int b = blockIdx.x, tid = threadIdx.x;
  int lane = tid & 63, w = tid >> 6;
  __shared__ float wsA[4], wsB[4], wsS[4];
  __shared__ float aL[256], uL[256];
  __shared__ float qsh[DD];
  __shared__ float qrow[QD];
  const size_t base = (size_t)b * TT_;

  // ---- window scan (t in [0, TSPEC)) ----
  float s = score[base + tid];
  float p  = 1.f / (1.f + expf(-s));      // sigmoid
  float om = 1.f / (1.f + expf(s));       // 1-p without cancellation
  float l = logf(fmaxf(om, TINYF));       // log(clip(1-p, TINY, 1))

  float inc = l;
  #pragma unroll
  for (int o = 1; o < 64; o <<= 1) {
    float n = __shfl_up(inc, o, 64);
    if (lane >= o) inc += n;
  }
  if (lane == 63) wsA[w] = inc;
  __syncthreads();
  float off = 0.f;
  #pragma unroll
  for (int j = 0; j < 4; ++j) if (j < w) off += wsA[j];
  float totA = wsA[0] + wsA[1] + wsA[2] + wsA[3];
  float cp = expf(off + inc - l);         // exclusive cumprod of (1-p)
  float den = prev[base + tid] / fminf(fmaxf(cp, 1e-10f), 1.f);

  float inc2 = den;
  #pragma unroll
  for (int o = 1; o < 64; o <<= 1) {
    float n = __shfl_up(inc2, o, 64);
    if (lane >= o) inc2 += n;
  }
  if (lane == 63) wsB[w] = inc2;
  __syncthreads();
  float off2 = 0.f;
  #pragma unroll
  for (int j = 0; j < 4; ++j) if (j < w) off2 += wsB[j];
  float totB = wsB[0] + wsB[1] + wsB[2] + wsB[3];

  float a = p * cp * (off2 + inc2);
  align_out[base + tid] = a;
  float sacc = a;
  aL[tid] = a;
  __syncthreads();

  // ---- window u accumulation: u[c=tid] += sum_t a[t]*value[b][t][c] ----
  float uacc = 0.f;
  {
    const float* vp = value + base * VD + tid;
    #pragma unroll 8
    for (int t = 0; t < TSPEC; ++t) uacc = fmaf(aL[t], vp[(size_t)t * VD], uacc);
  }

  float cL = totA, cD = totB;
  if (expf(cL) != 0.f) {
    // ======== FALLBACK (block-uniform; not taken on bench data) ========
    // q[b] + bq + bv
    qrow[tid]       = query[b * QD + tid];
    qrow[tid + 256] = query[b * QD + tid + 256];
    __syncthreads();
    {
      int h = tid >> 7, d = tid & 127;
      const float* wq = Wq + (size_t)(h * 256) * DD + d;
      const float* qr = qrow + h * 256;
      float acc = 0.f;
      #pragma unroll 8
      for (int c = 0; c < 256; ++c) acc = fmaf(qr[c], wq[(size_t)c * DD], acc);
      uL[tid] = acc;          // uL as scratch: tid == h*128+d
    }
    __syncthreads();
    if (tid < DD) qsh[tid] = uL[tid] + uL[DD + tid] + bq[tid] + bv[tid];
    __syncthreads();
    float sb = sbias[0];

    for (int ch = 1; ch < TT_ / 256; ++ch) {
      int t = ch * 256 + tid;
      // in-block score: slow per-thread row GEMV (correctness path only)
      const float* vrow = value + (base + t) * VD;
      float sc = sb;
      for (int d0 = 0; d0 < DD; d0 += 16) {
        float a16[16];
        #pragma unroll
        for (int j = 0; j < 16; ++j) a16[j] = qsh[d0 + j];
        for (int c = 0; c < VD; ++c) {
          float vv = vrow[c];
          const float* wv = Wv + (size_t)c * DD + d0;
          #pragma unroll
          for (int j = 0; j < 16; ++j) a16[j] = fmaf(vv, wv[j], a16[j]);
        }
        #pragma unroll
        for (int j = 0; j < 16; ++j) sc += attv[d0 + j] * tanhf(a16[j]);
      }
      // scan continuation
      float p2  = 1.f / (1.f + expf(-sc));
      float om2 = 1.f / (1.f + expf(sc));
      float l2  = logf(fmaxf(om2, TINYF));
      float i1 = l2;
      #pragma unroll
      for (int o = 1; o < 64; o <<= 1) {
        float n = __shfl_up(i1, o, 64);
        if (lane >= o) i1 += n;
      }
      if (lane == 63) wsA[w] = i1;
      __syncthreads();
      float of1 = 0.f;
      #pragma unroll
      for (int j = 0; j < 4; ++j) if (j < w) of1 += wsA[j];
      float tA = wsA[0] + wsA[1] + wsA[2] + wsA[3];
      float cp2 = expf(cL + of1 + i1 - l2);
      float dn2 = prev[base + t] / fminf(fmaxf(cp2, 1e-10f), 1.f);
      float i2 = dn2;
      #pragma unroll
      for (int o = 1; o < 64; o <<= 1) {
        float n = __shfl_up(i2, o, 64);
        if (lane >= o) i2 += n;
      }
      if (lane == 63) wsB[w] = i2;
      __syncthreads();
      float of2 = 0.f;
      #pragma unroll
      for (int j = 0; j < 4; ++j) if (j < w) of2 += wsB[j];
      float tB = wsB[0] + wsB[1] + wsB[2] + wsB[3];

      float a2 = p2 * cp2 * (cD + of2 + i2);
      align_out[base + t] = a2;
      sacc += a2;
      aL[tid] = a2;
      __syncthreads();
      const float* vp2 = value + (base + (size_t)ch * 256) * VD + tid;
      #pragma unroll 8
      for (int tt = 0; tt < 256; ++tt)
        uacc = fmaf(aL[tt], vp2[(size_t)tt * VD], uacc);
      cL += tA; cD += tB;
      __syncthreads();
    }
  } else {
    // ======== FAST PATH: alignment tail is exactly 0 ========
    float4 z = make_float4(0.f, 0.f, 0.f, 0.f);
    float4* dst = (float4*)(align_out + base + TSPEC);
    for (int i = tid; i < (TT_ - TSPEC) / 4; i += 256) dst[i] = z;
  }

  // ---- sum(alignment) reduce ----
  #pragma unroll
  for (int o = 32; o >= 1; o >>= 1) sacc += __shfl_xor(sacc, o, 64);
  if (lane == 0) wsS[w] = sacc;
  __syncthreads();
  float stot = wsS[0] + wsS[1] + wsS[2] + wsS[3];

  // ---- ctx[d] = sum_c u[c]*Wv[c][d] + stot*bv[d] ----
  uL[tid] = uacc;
  __syncthreads();
  if (tid < DD) {
    float c = stot * bv[tid];
    #pragma unroll 8
    for (int cc = 0; cc < VD; ++cc) c = fmaf(uL[cc], Wv[cc * DD + tid], c);
    ctx[b * DD + tid] = c;
  }
}

extern "C" void kernel_launch(void* const* d_in, const int* in_sizes, int n_in,
                              void* d_out, int out_size, void* d_ws, size_t ws_size,
                              hipStream_t stream) {
  const float* query = (const float*)d_in[0];
  const float* value = (const float*)d_in[1];
  const float* prev  = (const float*)d_in[2];
  const float* Wq    = (const float*)d_in[3];
  const float* bq    = (const float*)d_in[4];
  const float* Wv    = (const float*)d_in[5];
  const float* bv    = (const float*)d_in[6];
  const float* attv  = (const float*)d_in[7];
  const float* sbias = (const float*)d_in[8];

  float* ctx_out   = (float*)d_out;                 // [32][128]
  float* align_out = (float*)d_out + BB * DD;       // [32][8192]

  float* score = (float*)d_ws;                      // [32][8192] (window used)

  // node 1: speculative window scores (parallel, 128 blocks)
  k_score<<<dim3(TSPEC_TILES, BB), 256, 0, stream>>>(
      value, query, Wq, bq, Wv, bv, attv, sbias, score);

  // node 2: everything else (scan, tail zero-fill, u, ctx; in-block fallback)
  k_fused<<<BB, 256, 0, stream>>>(score, prev, value, query, Wq, bq, Wv, bv,
                                  attv, sbias, align_out, ctx_out);
}

// Round 4
// 3876.129 us; speedup vs baseline: 1.0174x; 1.0174x over previous
//
#include <hip/hip_runtime.h>
#include <hip/hip_bf16.h>
#include <math.h>

// Problem constants (from reference setup_inputs)
#define BB   32
#define TT_  8192
#define QD   512
#define VD   256
#define DD   128
#define TINYF 1.17549435e-38f

// Tiling for the score kernel
#define TTILE 64   // t rows per block
#define CCH   32   // c-chunk

// Speculation window: scores computed eagerly for t < TSPEC. E[log(1-p)]
// ~ -0.8/step -> cumsum ~ -200 at t=256, far below fp32 exp underflow (-104),
// ~15 sigma margin. If exp(cumsum) has NOT underflowed to exactly 0 at
// t=TSPEC, a scalar-guarded in-block fallback computes the remaining scores
// and scan chunks (slow but correct; never taken on this data distribution).
#define TSPEC 256
#define TSPEC_TILES (TSPEC / TTILE)   // 4

// ---------------- Kernel 1: window scores (q recomputed in-block) ----------
// score[b][t] = sum_d attv[d]*tanh(q[b][d]+bv[d] + (value[b][t]@Wv)[d]) + sbias
__global__ __launch_bounds__(256) void k_score(
    const float* __restrict__ value, const float* __restrict__ query,
    const float* __restrict__ Wq, const float* __restrict__ bq,
    const float* __restrict__ Wv, const float* __restrict__ bv,
    const float* __restrict__ attv, const float* __restrict__ sbias,
    float* __restrict__ score) {
  int b = blockIdx.y;
  int tid = threadIdx.x;

  // ---- recompute q[b][:] + bq + bv into LDS (cheap: 256 FMA/thread) ----
  __shared__ float qrow[QD];
  __shared__ float qpart[2][DD];
  __shared__ float qsh[DD];
  qrow[tid]       = query[b * QD + tid];
  qrow[tid + 256] = query[b * QD + tid + 256];
  __syncthreads();
  {
    int h = tid >> 7, d = tid & 127;
    const float* wq = Wq + (size_t)(h * 256) * DD + d;
    const float* qr = qrow + h * 256;
    float acc = 0.f;
    #pragma unroll 8
    for (int c = 0; c < 256; ++c) acc = fmaf(qr[c], wq[(size_t)c * DD], acc);
    qpart[h][d] = acc;
  }
  __syncthreads();
  if (tid < DD) qsh[tid] = qpart[0][tid] + qpart[1][tid] + bq[tid] + bv[tid];
  __syncthreads();

  // ---- register-tiled GEMM: (value tile) @ Wv ----
  int t0 = blockIdx.x * TTILE;
  int dq = tid & 31;   // d-group of 4
  int tq = tid >> 5;   // t-group of 8

  __shared__ float WvL[CCH * DD];
  __shared__ float valT[CCH * 68];

  float acc[8][4];
  #pragma unroll
  for (int i = 0; i < 8; ++i)
    #pragma unroll
    for (int j = 0; j < 4; ++j) acc[i][j] = 0.f;

  const float* vbase = value + ((size_t)b * TT_ + t0) * VD;

  for (int c0 = 0; c0 < VD; c0 += CCH) {
    const float4* wsrc = (const float4*)(Wv + (size_t)c0 * DD);
    float4* wdst = (float4*)WvL;
    #pragma unroll
    for (int k = 0; k < 4; ++k) wdst[tid + 256 * k] = wsrc[tid + 256 * k];
    #pragma unroll
    for (int k = 0; k < 2; ++k) {
      int id = tid * 2 + k;
      int tt = id >> 3;
      int c4 = id & 7;
      float4 vv = *(const float4*)(vbase + (size_t)tt * VD + c0 + c4 * 4);
      int cr = c4 * 4;
      valT[(cr + 0) * 68 + tt] = vv.x;
      valT[(cr + 1) * 68 + tt] = vv.y;
      valT[(cr + 2) * 68 + tt] = vv.z;
      valT[(cr + 3) * 68 + tt] = vv.w;
    }
    __syncthreads();
    #pragma unroll 4
    for (int cc = 0; cc < CCH; ++cc) {
      const float4 wv  = *(const float4*)(&WvL[cc * DD + dq * 4]);
      const float4 va0 = *(const float4*)(&valT[cc * 68 + tq * 8]);
      const float4 va1 = *(const float4*)(&valT[cc * 68 + tq * 8 + 4]);
      float va[8] = {va0.x, va0.y, va0.z, va0.w, va1.x, va1.y, va1.z, va1.w};
      #pragma unroll
      for (int i = 0; i < 8; ++i) {
        acc[i][0] = fmaf(va[i], wv.x, acc[i][0]);
        acc[i][1] = fmaf(va[i], wv.y, acc[i][1]);
        acc[i][2] = fmaf(va[i], wv.z, acc[i][2]);
        acc[i][3] = fmaf(va[i], wv.w, acc[i][3]);
      }
    }
    __syncthreads();
  }

  float sb = sbias[0];
  float qd[4], av[4];
  #pragma unroll
  for (int j = 0; j < 4; ++j) {
    int d = dq * 4 + j;
    qd[j] = qsh[d];
    av[j] = attv[d];
  }
  #pragma unroll
  for (int i = 0; i < 8; ++i) {
    float s = 0.f;
    #pragma unroll
    for (int j = 0; j < 4; ++j) {
      float x = qd[j] + acc[i][j];
      s += av[j] * tanhf(x);
    }
    #pragma unroll
    for (int m = 16; m >= 1; m >>= 1) s += __shfl_xor(s, m, 64);
    if (dq == 0) score[(size_t)b * TT_ + t0 + tq * 8 + i] = s + sb;
  }
}

// ------- Kernel 2: fused scan + tail-zero + u + ctx (+ scalar-guarded fallback)
__global__ __launch_bounds__(256) void k_fused(
    const float* __restrict__ score, const float* __restrict__ prev,
    const float* __restrict__ value, const float* __restrict__ query,
    const float* __restrict__ Wq, const float* __restrict__ bq,
    const float* __restrict__ Wv, const float* __restrict__ bv,
    const float* __restrict__ attv, const float* __restrict__ sbias,
    float* __restrict__ align_out, float* __restrict__ ctx) {
  int b = blockIdx.x, tid = threadIdx.x;
  int lane = tid & 63, w = tid >> 6;
  __shared__ float wsA[4], wsB[4], wsS[4];
  __shared__ float aL[256], uL[256];
  __shared__ float qsh[DD];
  __shared__ float qrow[QD];
  const size_t base = (size_t)b * TT_;

  // ---- window scan (t in [0, TSPEC)) ----
  float s = score[base + tid];
  float p  = 1.f / (1.f + expf(-s));      // sigmoid
  float om = 1.f / (1.f + expf(s));       // 1-p without cancellation
  float l = logf(fmaxf(om, TINYF));       // log(clip(1-p, TINY, 1))

  float inc = l;
  #pragma unroll
  for (int o = 1; o < 64; o <<= 1) {
    float n = __shfl_up(inc, o, 64);
    if (lane >= o) inc += n;
  }
  if (lane == 63) wsA[w] = inc;
  __syncthreads();
  float off = 0.f;
  #pragma unroll
  for (int j = 0; j < 4; ++j) if (j < w) off += wsA[j];
  float totA = wsA[0] + wsA[1] + wsA[2] + wsA[3];
  float cp = expf(off + inc - l);         // exclusive cumprod of (1-p)
  float den = prev[base + tid] / fminf(fmaxf(cp, 1e-10f), 1.f);

  float inc2 = den;
  #pragma unroll
  for (int o = 1; o < 64; o <<= 1) {
    float n = __shfl_up(inc2, o, 64);
    if (lane >= o) inc2 += n;
  }
  if (lane == 63) wsB[w] = inc2;
  __syncthreads();
  float off2 = 0.f;
  #pragma unroll
  for (int j = 0; j < 4; ++j) if (j < w) off2 += wsB[j];
  float totB = wsB[0] + wsB[1] + wsB[2] + wsB[3];

  float a = p * cp * (off2 + inc2);
  align_out[base + tid] = a;
  float sacc = a;
  aL[tid] = a;
  __syncthreads();

  // ---- window u accumulation: u[c=tid] += sum_t a[t]*value[b][t][c] ----
  float uacc = 0.f;
  {
    const float* vp = value + base * VD + tid;
    #pragma unroll 8
    for (int t = 0; t < TSPEC; ++t) uacc = fmaf(aL[t], vp[(size_t)t * VD], uacc);
  }

  float cL = totA, cD = totB;
  // Scalar (SGPR) guard: all threads compute the identical value from shared
  // wsA, but the compiler can't prove that. readfirstlane -> s_cmp/s_cbranch
  // so the cold fallback body (which contains barriers) is genuinely skipped.
  // R3 lesson: a VGPR guard here made every wave traverse the ~1.3M-inst dead
  // fallback structure => 3.6 ms.
  int fb = __builtin_amdgcn_readfirstlane((expf(cL) != 0.f) ? 1 : 0);
  if (fb) {
    // ======== FALLBACK (block-uniform; not taken on bench data) ========
    qrow[tid]       = query[b * QD + tid];
    qrow[tid + 256] = query[b * QD + tid + 256];
    __syncthreads();
    {
      int h = tid >> 7, d = tid & 127;
      const float* wq = Wq + (size_t)(h * 256) * DD + d;
      const float* qr = qrow + h * 256;
      float acc = 0.f;
      for (int c = 0; c < 256; ++c) acc = fmaf(qr[c], wq[(size_t)c * DD], acc);
      uL[tid] = acc;          // uL as scratch: tid == h*128+d
    }
    __syncthreads();
    if (tid < DD) qsh[tid] = uL[tid] + uL[DD + tid] + bq[tid] + bv[tid];
    __syncthreads();
    float sb = sbias[0];

    for (int ch = 1; ch < TT_ / 256; ++ch) {
      int t = ch * 256 + tid;
      // in-block score: per-thread row GEMV (correctness path only)
      const float* vrow = value + (base + t) * VD;
      float sc = sb;
      for (int d0 = 0; d0 < DD; d0 += 16) {
        float a16[16];
        #pragma unroll
        for (int j = 0; j < 16; ++j) a16[j] = qsh[d0 + j];
        for (int c = 0; c < VD; ++c) {
          float vv = vrow[c];
          const float* wv = Wv + (size_t)c * DD + d0;
          #pragma unroll
          for (int j = 0; j < 16; ++j) a16[j] = fmaf(vv, wv[j], a16[j]);
        }
        #pragma unroll
        for (int j = 0; j < 16; ++j) sc += attv[d0 + j] * tanhf(a16[j]);
      }
      // scan continuation
      float p2  = 1.f / (1.f + expf(-sc));
      float om2 = 1.f / (1.f + expf(sc));
      float l2  = logf(fmaxf(om2, TINYF));
      float i1 = l2;
      #pragma unroll
      for (int o = 1; o < 64; o <<= 1) {
        float n = __shfl_up(i1, o, 64);
        if (lane >= o) i1 += n;
      }
      if (lane == 63) wsA[w] = i1;
      __syncthreads();
      float of1 = 0.f;
      #pragma unroll
      for (int j = 0; j < 4; ++j) if (j < w) of1 += wsA[j];
      float tA = wsA[0] + wsA[1] + wsA[2] + wsA[3];
      float cp2 = expf(cL + of1 + i1 - l2);
      float dn2 = prev[base + t] / fminf(fmaxf(cp2, 1e-10f), 1.f);
      float i2 = dn2;
      #pragma unroll
      for (int o = 1; o < 64; o <<= 1) {
        float n = __shfl_up(i2, o, 64);
        if (lane >= o) i2 += n;
      }
      if (lane == 63) wsB[w] = i2;
      __syncthreads();
      float of2 = 0.f;
      #pragma unroll
      for (int j = 0; j < 4; ++j) if (j < w) of2 += wsB[j];
      float tB = wsB[0] + wsB[1] + wsB[2] + wsB[3];

      float a2 = p2 * cp2 * (cD + of2 + i2);
      align_out[base + t] = a2;
      sacc += a2;
      aL[tid] = a2;
      __syncthreads();
      const float* vp2 = value + (base + (size_t)ch * 256) * VD + tid;
      for (int tt = 0; tt < 256; ++tt)
        uacc = fmaf(aL[tt], vp2[(size_t)tt * VD], uacc);
      cL += tA; cD += tB;
      __syncthreads();
    }
  } else {
    // ======== FAST PATH: alignment tail is exactly 0 ========
    float4 z = make_float4(0.f, 0.f, 0.f, 0.f);
    float4* dst = (float4*)(align_out + base + TSPEC);
    for (int i = tid; i < (TT_ - TSPEC) / 4; i += 256) dst[i] = z;
  }

  // ---- sum(alignment) reduce ----
  #pragma unroll
  for (int o = 32; o >= 1; o >>= 1) sacc += __shfl_xor(sacc, o, 64);
  if (lane == 0) wsS[w] = sacc;
  __syncthreads();
  float stot = wsS[0] + wsS[1] + wsS[2] + wsS[3];

  // ---- ctx[d] = sum_c u[c]*Wv[c][d] + stot*bv[d] ----
  uL[tid] = uacc;
  __syncthreads();
  if (tid < DD) {
    float c = stot * bv[tid];
    #pragma unroll 8
    for (int cc = 0; cc < VD; ++cc) c = fmaf(uL[cc], Wv[cc * DD + tid], c);
    ctx[b * DD + tid] = c;
  }
}

extern "C" void kernel_launch(void* const* d_in, const int* in_sizes, int n_in,
                              void* d_out, int out_size, void* d_ws, size_t ws_size,
                              hipStream_t stream) {
  const float* query = (const float*)d_in[0];
  const float* value = (const float*)d_in[1];
  const float* prev  = (const float*)d_in[2];
  const float* Wq    = (const float*)d_in[3];
  const float* bq    = (const float*)d_in[4];
  const float* Wv    = (const float*)d_in[5];
  const float* bv    = (const float*)d_in[6];
  const float* attv  = (const float*)d_in[7];
  const float* sbias = (const float*)d_in[8];

  float* ctx_out   = (float*)d_out;                 // [32][128]
  float* align_out = (float*)d_out + BB * DD;       // [32][8192]

  float* score = (float*)d_ws;                      // [32][8192] (window used)

  // node 1: speculative window scores (parallel, 128 blocks)
  k_score<<<dim3(TSPEC_TILES, BB), 256, 0, stream>>>(
      value, query, Wq, bq, Wv, bv, attv, sbias, score);

  // node 2: everything else (scan, tail zero-fill, u, ctx; scalar-guarded
  // in-block fallback)
  k_fused<<<BB, 256, 0, stream>>>(score, prev, value, query, Wq, bq, Wv, bv,
                                  attv, sbias, align_out, ctx_out);
}

// Round 5
// 378.769 us; speedup vs baseline: 10.4119x; 10.2335x over previous
//
#include <hip/hip_runtime.h>
#include <hip/hip_bf16.h>
#include <math.h>

// Problem constants (from reference setup_inputs)
#define BB   32
#define TT_  8192
#define QD   512
#define VD   256
#define DD   128
#define TINYF 1.17549435e-38f

// Tiling for the score kernel
#define TTILE 64   // t rows per block
#define CCH   32   // c-chunk

// Speculation window. R4 lesson: at TSPEC=256, a per-b mean score shift
// (mu_b ~ N(0,0.26)) makes "no fp32 underflow of cumprod by t=256" a ~2-sigma
// event => fallback taken for ~1 of 32 b. At TSPEC=512 the requirement is
// ~4.6 sigma => effectively never (R1 empirically all-fast). Fallback stays
// as PARALLEL guarded kernels (R3/R4 lesson: an in-block single-CU fallback
// cost 3.6 ms when taken).
#define TSPEC 512
#define TSPEC_TILES (TSPEC / TTILE)           // 8
#define TSPEC_CHUNKS (TSPEC / 256)            // 2

// ---------------- Kernel 1: scores (q recomputed in-block) ------------------
// score[b][t] = sum_d attv[d]*tanh(q[b][d]+bv[d] + (value[b][t]@Wv)[d]) + sbias
// grid: (tiles, B); flags!=null -> early-exit when flags[b]==0.
__global__ __launch_bounds__(256) void k_score(
    const float* __restrict__ value, const float* __restrict__ query,
    const float* __restrict__ Wq, const float* __restrict__ bq,
    const float* __restrict__ Wv, const float* __restrict__ bv,
    const float* __restrict__ attv, const float* __restrict__ sbias,
    float* __restrict__ score, int t_tile_base, const int* __restrict__ flags) {
  int b = blockIdx.y;
  if (flags && flags[b] == 0) return;
  int tid = threadIdx.x;

  // ---- recompute q[b][:] + bq + bv into LDS (cheap: 256 FMA/thread) ----
  __shared__ float qrow[QD];
  __shared__ float qpart[2][DD];
  __shared__ float qsh[DD];
  qrow[tid]       = query[b * QD + tid];
  qrow[tid + 256] = query[b * QD + tid + 256];
  __syncthreads();
  {
    int h = tid >> 7, d = tid & 127;
    const float* wq = Wq + (size_t)(h * 256) * DD + d;
    const float* qr = qrow + h * 256;
    float acc = 0.f;
    #pragma unroll 8
    for (int c = 0; c < 256; ++c) acc = fmaf(qr[c], wq[(size_t)c * DD], acc);
    qpart[h][d] = acc;
  }
  __syncthreads();
  if (tid < DD) qsh[tid] = qpart[0][tid] + qpart[1][tid] + bq[tid] + bv[tid];
  __syncthreads();

  // ---- register-tiled GEMM: (value tile) @ Wv ----
  int t0 = (t_tile_base + blockIdx.x) * TTILE;
  int dq = tid & 31;   // d-group of 4
  int tq = tid >> 5;   // t-group of 8

  __shared__ float WvL[CCH * DD];
  __shared__ float valT[CCH * 68];

  float acc[8][4];
  #pragma unroll
  for (int i = 0; i < 8; ++i)
    #pragma unroll
    for (int j = 0; j < 4; ++j) acc[i][j] = 0.f;

  const float* vbase = value + ((size_t)b * TT_ + t0) * VD;

  for (int c0 = 0; c0 < VD; c0 += CCH) {
    const float4* wsrc = (const float4*)(Wv + (size_t)c0 * DD);
    float4* wdst = (float4*)WvL;
    #pragma unroll
    for (int k = 0; k < 4; ++k) wdst[tid + 256 * k] = wsrc[tid + 256 * k];
    #pragma unroll
    for (int k = 0; k < 2; ++k) {
      int id = tid * 2 + k;
      int tt = id >> 3;
      int c4 = id & 7;
      float4 vv = *(const float4*)(vbase + (size_t)tt * VD + c0 + c4 * 4);
      int cr = c4 * 4;
      valT[(cr + 0) * 68 + tt] = vv.x;
      valT[(cr + 1) * 68 + tt] = vv.y;
      valT[(cr + 2) * 68 + tt] = vv.z;
      valT[(cr + 3) * 68 + tt] = vv.w;
    }
    __syncthreads();
    #pragma unroll 4
    for (int cc = 0; cc < CCH; ++cc) {
      const float4 wv  = *(const float4*)(&WvL[cc * DD + dq * 4]);
      const float4 va0 = *(const float4*)(&valT[cc * 68 + tq * 8]);
      const float4 va1 = *(const float4*)(&valT[cc * 68 + tq * 8 + 4]);
      float va[8] = {va0.x, va0.y, va0.z, va0.w, va1.x, va1.y, va1.z, va1.w};
      #pragma unroll
      for (int i = 0; i < 8; ++i) {
        acc[i][0] = fmaf(va[i], wv.x, acc[i][0]);
        acc[i][1] = fmaf(va[i], wv.y, acc[i][1]);
        acc[i][2] = fmaf(va[i], wv.z, acc[i][2]);
        acc[i][3] = fmaf(va[i], wv.w, acc[i][3]);
      }
    }
    __syncthreads();
  }

  float sb = sbias[0];
  float qd[4], av[4];
  #pragma unroll
  for (int j = 0; j < 4; ++j) {
    int d = dq * 4 + j;
    qd[j] = qsh[d];
    av[j] = attv[d];
  }
  #pragma unroll
  for (int i = 0; i < 8; ++i) {
    float s = 0.f;
    #pragma unroll
    for (int j = 0; j < 4; ++j) {
      float x = qd[j] + acc[i][j];
      s += av[j] * tanhf(x);
    }
    #pragma unroll
    for (int m = 16; m >= 1; m >>= 1) s += __shfl_xor(s, m, 64);
    if (dq == 0) score[(size_t)b * TT_ + t0 + tq * 8 + i] = s + sb;
  }
}

// ------- Kernel 2: fused window scan + tail-zero + u + ctx ------------------
// Fast path (cumprod underflowed by TSPEC): completes everything for b.
// Else: stores carries + window-u, sets flags[b]=1 for the fallback chain.
__global__ __launch_bounds__(256) void k_fused(
    const float* __restrict__ score, const float* __restrict__ prev,
    const float* __restrict__ value, const float* __restrict__ Wv,
    const float* __restrict__ bv,
    float* __restrict__ align_out, float* __restrict__ ctx,
    float* __restrict__ suma, float* __restrict__ carryL,
    float* __restrict__ carryD, float* __restrict__ uws,
    int* __restrict__ flags) {
  int b = blockIdx.x, tid = threadIdx.x;
  int lane = tid & 63, w = tid >> 6;
  __shared__ float wsA[4], wsB[4], wsS[4];
  __shared__ float aL[256], uL[256];
  const size_t base = (size_t)b * TT_;

  float cL = 0.f, cD = 0.f, sacc = 0.f, uacc = 0.f;

  for (int ch = 0; ch < TSPEC_CHUNKS; ++ch) {
    int t = ch * 256 + tid;
    float s = score[base + t];
    float p  = 1.f / (1.f + expf(-s));      // sigmoid
    float om = 1.f / (1.f + expf(s));       // 1-p without cancellation
    float l = logf(fmaxf(om, TINYF));       // log(clip(1-p, TINY, 1))

    float inc = l;
    #pragma unroll
    for (int o = 1; o < 64; o <<= 1) {
      float n = __shfl_up(inc, o, 64);
      if (lane >= o) inc += n;
    }
    if (lane == 63) wsA[w] = inc;
    __syncthreads();
    float off = 0.f;
    #pragma unroll
    for (int j = 0; j < 4; ++j) if (j < w) off += wsA[j];
    float totA = wsA[0] + wsA[1] + wsA[2] + wsA[3];
    float cp = expf(cL + off + inc - l);    // exclusive cumprod of (1-p)
    float den = prev[base + t] / fminf(fmaxf(cp, 1e-10f), 1.f);

    float inc2 = den;
    #pragma unroll
    for (int o = 1; o < 64; o <<= 1) {
      float n = __shfl_up(inc2, o, 64);
      if (lane >= o) inc2 += n;
    }
    if (lane == 63) wsB[w] = inc2;
    __syncthreads();
    float off2 = 0.f;
    #pragma unroll
    for (int j = 0; j < 4; ++j) if (j < w) off2 += wsB[j];
    float totB = wsB[0] + wsB[1] + wsB[2] + wsB[3];

    float a = p * cp * (cD + off2 + inc2);
    align_out[base + t] = a;
    sacc += a;
    aL[tid] = a;
    __syncthreads();

    // u[c=tid] += sum_t a[t]*value[b][ch*256+t][c]  (coalesced across threads)
    const float* vp = value + (base + (size_t)ch * 256) * VD + tid;
    #pragma unroll 8
    for (int tt = 0; tt < 256; ++tt)
      uacc = fmaf(aL[tt], vp[(size_t)tt * VD], uacc);

    cL += totA; cD += totB;
    __syncthreads();   // protect wsA/wsB/aL before next chunk
  }

  // ---- sum(alignment) reduce ----
  #pragma unroll
  for (int o = 32; o >= 1; o >>= 1) sacc += __shfl_xor(sacc, o, 64);
  if (lane == 0) wsS[w] = sacc;
  __syncthreads();
  float stot = wsS[0] + wsS[1] + wsS[2] + wsS[3];

  // Block-uniform decision, forced scalar so barriers stay outside divergence.
  int fb = __builtin_amdgcn_readfirstlane((expf(cL) != 0.f) ? 1 : 0);

  if (fb) {
    // fallback chain finishes this b; save state
    if (tid == 0) { flags[b] = 1; suma[b] = stot; carryL[b] = cL; carryD[b] = cD; }
    uws[b * VD + tid] = uacc;     // window part of u
  } else {
    if (tid == 0) { flags[b] = 0; suma[b] = stot; }
    // zero-fill alignment tail
    float4 z = make_float4(0.f, 0.f, 0.f, 0.f);
    float4* dst = (float4*)(align_out + base + TSPEC);
    for (int i = tid; i < (TT_ - TSPEC) / 4; i += 256) dst[i] = z;
  }

  uL[tid] = uacc;
  __syncthreads();
  if (!fb && tid < DD) {
    float c = stot * bv[tid];
    #pragma unroll 8
    for (int cc = 0; cc < VD; ++cc) c = fmaf(uL[cc], Wv[cc * DD + tid], c);
    ctx[b * DD + tid] = c;
  }
}

// ---------------- Kernel 3: scan continuation (fallback only) ---------------
__global__ __launch_bounds__(256) void k_scan1(
    const float* __restrict__ score, const float* __restrict__ prev,
    float* __restrict__ align_out, float* __restrict__ suma,
    const float* __restrict__ carryL, const float* __restrict__ carryD,
    const int* __restrict__ flags) {
  int b = blockIdx.x, tid = threadIdx.x;
  if (flags[b] == 0) return;
  int lane = tid & 63, w = tid >> 6;
  __shared__ float wsA[4], wsB[4];
  float cL = carryL[b], cD = carryD[b], sacc = suma[b];
  const size_t base = (size_t)b * TT_;

  for (int ch = TSPEC_CHUNKS; ch < TT_ / 256; ++ch) {
    int t = ch * 256 + tid;
    float s = score[base + t];
    float p  = 1.f / (1.f + expf(-s));
    float om = 1.f / (1.f + expf(s));
    float l = logf(fmaxf(om, TINYF));

    float inc = l;
    #pragma unroll
    for (int o = 1; o < 64; o <<= 1) {
      float n = __shfl_up(inc, o, 64);
      if (lane >= o) inc += n;
    }
    if (lane == 63) wsA[w] = inc;
    __syncthreads();
    float off = 0.f;
    #pragma unroll
    for (int j = 0; j < 4; ++j) if (j < w) off += wsA[j];
    float totA = wsA[0] + wsA[1] + wsA[2] + wsA[3];
    float cp = expf(cL + off + inc - l);
    float den = prev[base + t] / fminf(fmaxf(cp, 1e-10f), 1.f);

    float inc2 = den;
    #pragma unroll
    for (int o = 1; o < 64; o <<= 1) {
      float n = __shfl_up(inc2, o, 64);
      if (lane >= o) inc2 += n;
    }
    if (lane == 63) wsB[w] = inc2;
    __syncthreads();
    float off2 = 0.f;
    #pragma unroll
    for (int j = 0; j < 4; ++j) if (j < w) off2 += wsB[j];
    float totB = wsB[0] + wsB[1] + wsB[2] + wsB[3];

    float a = p * cp * (cD + off2 + inc2);
    align_out[base + t] = a;
    sacc += a;
    cL += totA; cD += totB;
    __syncthreads();
  }

  #pragma unroll
  for (int o = 32; o >= 1; o >>= 1) sacc += __shfl_xor(sacc, o, 64);
  if (lane == 0) wsA[w] = sacc;
  __syncthreads();
  if (tid == 0) suma[b] = wsA[0] + wsA[1] + wsA[2] + wsA[3];
}

// ---------------- Kernel 4: u + context for fallback b ----------------------
__global__ __launch_bounds__(256) void k_uctx_fb(
    const float* __restrict__ value, const float* __restrict__ align,
    const float* __restrict__ Wv, const float* __restrict__ bv,
    const float* __restrict__ suma, const float* __restrict__ uws,
    float* __restrict__ ctx, const int* __restrict__ flags) {
  int b = blockIdx.x, tid = threadIdx.x;
  if (flags[b] == 0) return;
  __shared__ float aL[256];
  __shared__ float uL[256];
  __shared__ int any;
  const size_t base = (size_t)b * TT_;
  float acc = uws[b * VD + tid];   // window part (t < TSPEC)
  for (int ch = TSPEC_CHUNKS; ch < TT_ / 256; ++ch) {
    if (tid == 0) any = 0;
    __syncthreads();
    float a = align[base + ch * 256 + tid];
    aL[tid] = a;
    if (a != 0.f) any = 1;  // benign same-value race
    __syncthreads();
    if (any) {
      const float* vp = value + (base + (size_t)ch * 256) * VD + tid;
      #pragma unroll 8
      for (int t = 0; t < 256; ++t) acc = fmaf(aL[t], vp[(size_t)t * VD], acc);
    }
    __syncthreads();
  }
  uL[tid] = acc;
  __syncthreads();
  if (tid < DD) {
    float c = suma[b] * bv[tid];
    #pragma unroll 8
    for (int cc = 0; cc < VD; ++cc) c = fmaf(uL[cc], Wv[cc * DD + tid], c);
    ctx[b * DD + tid] = c;
  }
}

extern "C" void kernel_launch(void* const* d_in, const int* in_sizes, int n_in,
                              void* d_out, int out_size, void* d_ws, size_t ws_size,
                              hipStream_t stream) {
  const float* query = (const float*)d_in[0];
  const float* value = (const float*)d_in[1];
  const float* prev  = (const float*)d_in[2];
  const float* Wq    = (const float*)d_in[3];
  const float* bq    = (const float*)d_in[4];
  const float* Wv    = (const float*)d_in[5];
  const float* bv    = (const float*)d_in[6];
  const float* attv  = (const float*)d_in[7];
  const float* sbias = (const float*)d_in[8];

  float* ctx_out   = (float*)d_out;                 // [32][128]
  float* align_out = (float*)d_out + BB * DD;       // [32][8192]

  float* ws = (float*)d_ws;
  float* score  = ws;                  // 262144
  float* suma   = ws + 262144;         // 32
  float* carryL = ws + 262176;         // 32
  float* carryD = ws + 262208;         // 32
  int*   flags  = (int*)(ws + 262240); // 32
  float* uws    = ws + 262272;         // 8192

  // node 1: speculative window scores, t < TSPEC (256 blocks)
  k_score<<<dim3(TSPEC_TILES, BB), 256, 0, stream>>>(
      value, query, Wq, bq, Wv, bv, attv, sbias, score, 0, nullptr);

  // node 2: window scan + tail-zero + u + ctx (fast path completes all)
  k_fused<<<BB, 256, 0, stream>>>(score, prev, value, Wv, bv, align_out,
                                  ctx_out, suma, carryL, carryD, uws, flags);

  // nodes 3-5: fallback chain, per-b early-exit (near-free when unflagged)
  k_score<<<dim3((TT_ - TSPEC) / TTILE, BB), 256, 0, stream>>>(
      value, query, Wq, bq, Wv, bv, attv, sbias, score, TSPEC_TILES, flags);
  k_scan1<<<BB, 256, 0, stream>>>(score, prev, align_out, suma,
                                  carryL, carryD, flags);
  k_uctx_fb<<<BB, 256, 0, stream>>>(value, align_out, Wv, bv, suma, uws,
                                    ctx_out, flags);
}